// Round 8
// baseline (454.444 us; speedup 1.0000x reference)
//
#include <hip/hip_runtime.h>

// B=8, N=2048, D=F=768. out = softmax((X Wq)(X Wk)^T) (X Wv), fp32 I/O.
// Identity: S[q][k] = sum_d X[q][d] * H[k][d],  H = X * M^T,  M = Wq Wk^T.
// ws: H = fp16(X M^T) [16384][768] | Vt = fp16(X Wv)^T [8][768][2048]  (50,331,648 B)
// d_out scratch (consumed before attn writes out): Mh fp16 @0 | WvT fp16 @2359296 |
//   Xh = fp16(X) @4194304 (25 MB).
// v12: (a) proj_h/proj_v double-buffered: 1 barrier/K-step, global loads issued
//   before MFMA + LDS-written after (T14 issue-early/write-late) -> latency hidden.
//   (b) attn ring tails prefetch NEXT m0 tile (K during S, V during PV) instead of
//   dummy-reloading chunk 0; per-iter init loads removed. Same load count, issue->
//   consume distance ~0 -> ~1 phase. attn otherwise identical to v10 (267us).

typedef __attribute__((ext_vector_type(8))) _Float16 half8;
typedef __attribute__((ext_vector_type(4))) _Float16 half4v;
typedef __attribute__((ext_vector_type(4))) float floatx4;

__device__ __forceinline__ _Float16 f2h(float f) { return (_Float16)f; }
#define MFMA16 __builtin_amdgcn_mfma_f32_16x16x32_f16

// ---------------- Xh = fp16(X), 12.58M elements ----------------
__global__ __launch_bounds__(256) void cast_x_kernel(const float* __restrict__ X,
    _Float16* __restrict__ Xh) {
  size_t idx = (size_t)blockIdx.x * 256 + threadIdx.x;
  for (size_t o8 = idx; o8 < 1572864u; o8 += 524288u) {
    size_t o = o8 * 8;
    float4 a = *(const float4*)(X + o);
    float4 b = *(const float4*)(X + o + 4);
    *(half8*)(Xh + o) = (half8){f2h(a.x), f2h(a.y), f2h(a.z), f2h(a.w),
                                f2h(b.x), f2h(b.y), f2h(b.z), f2h(b.w)};
  }
}

// ---------------- Mh[d][e] = fp16(Wq Wk^T) ----------------
__global__ __launch_bounds__(256) void mm_small_kernel(const float* __restrict__ Wq,
    const float* __restrict__ Wk, _Float16* __restrict__ Mh) {
  __shared__ _Float16 As[128][72];
  __shared__ _Float16 Bs[128][72];
  int bn = blockIdx.x, bm = blockIdx.y;
  int tid = threadIdx.x, lane = tid & 63, wave = tid >> 6;
  int wm = wave >> 1, wn = wave & 1;
  int l15 = lane & 15, quad = lane >> 4;
  floatx4 acc[16];
  for (int i = 0; i < 16; i++) acc[i] = (floatx4){0.f, 0.f, 0.f, 0.f};
  for (int k0 = 0; k0 < 768; k0 += 64) {
    __syncthreads();
    for (int i = 0; i < 8; i++) {
      int f = i * 256 + tid;
      int row = f >> 4, c4 = (f & 15) << 2;
      float4 va = *(const float4*)(Wq + (size_t)(bm * 128 + row) * 768 + k0 + c4);
      *(half4v*)&As[row][c4] = (half4v){f2h(va.x), f2h(va.y), f2h(va.z), f2h(va.w)};
      float4 vb = *(const float4*)(Wk + (size_t)(bn * 128 + row) * 768 + k0 + c4);
      *(half4v*)&Bs[row][c4] = (half4v){f2h(vb.x), f2h(vb.y), f2h(vb.z), f2h(vb.w)};
    }
    __syncthreads();
    for (int kk = 0; kk < 2; kk++) {
      half8 a[4], b[4];
      for (int mt = 0; mt < 4; mt++) a[mt] = *(half8*)&As[wm * 64 + mt * 16 + l15][kk * 32 + quad * 8];
      for (int nt = 0; nt < 4; nt++) b[nt] = *(half8*)&Bs[wn * 64 + nt * 16 + l15][kk * 32 + quad * 8];
      for (int mt = 0; mt < 4; mt++)
        for (int nt = 0; nt < 4; nt++)
          acc[mt * 4 + nt] = MFMA16(a[mt], b[nt], acc[mt * 4 + nt], 0, 0, 0);
    }
  }
  for (int mt = 0; mt < 4; mt++)
    for (int nt = 0; nt < 4; nt++) {
      int e = bn * 128 + wn * 64 + nt * 16 + l15;
      for (int r = 0; r < 4; r++) {
        int d = bm * 128 + wm * 64 + mt * 16 + quad * 4 + r;
        Mh[(size_t)d * 768 + e] = f2h(acc[mt * 4 + nt][r]);
      }
    }
}

// ---------------- WvT[e][d] = Wv[d][e], fp16 ----------------
__global__ void pack_wv_kernel(const float* __restrict__ Wv, _Float16* __restrict__ WvT) {
  __shared__ float tile[32][33];
  int k0 = blockIdx.x * 32;
  int n0 = blockIdx.y * 32;
  int tx = threadIdx.x, ty = threadIdx.y;
  for (int yy = ty; yy < 32; yy += 8)
    tile[yy][tx] = Wv[(size_t)(k0 + yy) * 768 + n0 + tx];
  __syncthreads();
  for (int yy = ty; yy < 32; yy += 8)
    WvT[(size_t)(n0 + yy) * 768 + k0 + tx] = f2h(tile[tx][yy]);
}

// ---------------- H = Xh * Mh^T (double-buffered, 1 barrier/K-step) ----------------
__global__ __launch_bounds__(256) void proj_h_kernel(const _Float16* __restrict__ Xh,
    const _Float16* __restrict__ Mh, _Float16* __restrict__ H) {
  __shared__ _Float16 As[2][128][72];
  __shared__ _Float16 Bs[2][128][72];   // 73,728 B -> 2 blocks/CU
  int bn = blockIdx.x, bm = blockIdx.y;
  int tid = threadIdx.x, lane = tid & 63, wave = tid >> 6;
  int wm = wave >> 1, wn = wave & 1;
  int l15 = lane & 15, quad = lane >> 4;
  floatx4 acc[16];
  for (int i = 0; i < 16; i++) acc[i] = (floatx4){0.f, 0.f, 0.f, 0.f};
  half8 ra[4], rb[4];
  #pragma unroll
  for (int i = 0; i < 4; i++) {
    int f = i * 256 + tid, row = f >> 3, c8 = (f & 7) << 3;
    ra[i] = *(const half8*)(Xh + (size_t)(bm * 128 + row) * 768 + c8);
    rb[i] = *(const half8*)(Mh + (size_t)(bn * 128 + row) * 768 + c8);
  }
  #pragma unroll
  for (int i = 0; i < 4; i++) {
    int f = i * 256 + tid, row = f >> 3, c8 = (f & 7) << 3;
    *(half8*)&As[0][row][c8] = ra[i];
    *(half8*)&Bs[0][row][c8] = rb[i];
  }
  __syncthreads();
  int cur = 0;
  for (int t = 0; t < 12; t++) {
    if (t < 11) {   // issue next-tile loads BEFORE compute (latency hides under MFMA)
      int k0 = (t + 1) * 64;
      #pragma unroll
      for (int i = 0; i < 4; i++) {
        int f = i * 256 + tid, row = f >> 3, c8 = (f & 7) << 3;
        ra[i] = *(const half8*)(Xh + (size_t)(bm * 128 + row) * 768 + k0 + c8);
        rb[i] = *(const half8*)(Mh + (size_t)(bn * 128 + row) * 768 + k0 + c8);
      }
    }
    #pragma unroll
    for (int kk = 0; kk < 2; kk++) {
      half8 a[4], b[4];
      #pragma unroll
      for (int mt = 0; mt < 4; mt++) a[mt] = *(half8*)&As[cur][wm * 64 + mt * 16 + l15][kk * 32 + quad * 8];
      #pragma unroll
      for (int nt = 0; nt < 4; nt++) b[nt] = *(half8*)&Bs[cur][wn * 64 + nt * 16 + l15][kk * 32 + quad * 8];
      #pragma unroll
      for (int mt = 0; mt < 4; mt++)
        #pragma unroll
        for (int nt = 0; nt < 4; nt++)
          acc[mt * 4 + nt] = MFMA16(a[mt], b[nt], acc[mt * 4 + nt], 0, 0, 0);
    }
    if (t < 11) {   // write-late into the other buffer; single barrier per step
      #pragma unroll
      for (int i = 0; i < 4; i++) {
        int f = i * 256 + tid, row = f >> 3, c8 = (f & 7) << 3;
        *(half8*)&As[cur ^ 1][row][c8] = ra[i];
        *(half8*)&Bs[cur ^ 1][row][c8] = rb[i];
      }
      __syncthreads();
      cur ^= 1;
    }
  }
  for (int mt = 0; mt < 4; mt++)
    for (int nt = 0; nt < 4; nt++) {
      int col = bn * 128 + wn * 64 + nt * 16 + l15;
      for (int r = 0; r < 4; r++) {
        int row = bm * 128 + wm * 64 + mt * 16 + quad * 4 + r;
        H[(size_t)row * 768 + col] = f2h(acc[mt * 4 + nt][r]);
      }
    }
}

// ---------------- Vt[b][d][n] = fp16(Xh * WvT^T)^T (double-buffered) ----------------
__global__ __launch_bounds__(256) void proj_v_kernel(const _Float16* __restrict__ Xh,
    const _Float16* __restrict__ WvT, _Float16* __restrict__ Vt) {
  __shared__ _Float16 As[2][128][72];
  __shared__ _Float16 Bs[2][128][72];
  int bn = blockIdx.x, bm = blockIdx.y;
  int tid = threadIdx.x, lane = tid & 63, wave = tid >> 6;
  int wm = wave >> 1, wn = wave & 1;
  int l15 = lane & 15, quad = lane >> 4;
  floatx4 acc[16];
  for (int i = 0; i < 16; i++) acc[i] = (floatx4){0.f, 0.f, 0.f, 0.f};
  half8 ra[4], rb[4];
  #pragma unroll
  for (int i = 0; i < 4; i++) {
    int f = i * 256 + tid, row = f >> 3, c8 = (f & 7) << 3;
    ra[i] = *(const half8*)(Xh + (size_t)(bm * 128 + row) * 768 + c8);
    rb[i] = *(const half8*)(WvT + (size_t)(bn * 128 + row) * 768 + c8);
  }
  #pragma unroll
  for (int i = 0; i < 4; i++) {
    int f = i * 256 + tid, row = f >> 3, c8 = (f & 7) << 3;
    *(half8*)&As[0][row][c8] = ra[i];
    *(half8*)&Bs[0][row][c8] = rb[i];
  }
  __syncthreads();
  int cur = 0;
  for (int t = 0; t < 12; t++) {
    if (t < 11) {
      int k0 = (t + 1) * 64;
      #pragma unroll
      for (int i = 0; i < 4; i++) {
        int f = i * 256 + tid, row = f >> 3, c8 = (f & 7) << 3;
        ra[i] = *(const half8*)(Xh + (size_t)(bm * 128 + row) * 768 + k0 + c8);
        rb[i] = *(const half8*)(WvT + (size_t)(bn * 128 + row) * 768 + k0 + c8);
      }
    }
    #pragma unroll
    for (int kk = 0; kk < 2; kk++) {
      half8 a[4], b[4];
      #pragma unroll
      for (int mt = 0; mt < 4; mt++) a[mt] = *(half8*)&As[cur][wm * 64 + mt * 16 + l15][kk * 32 + quad * 8];
      #pragma unroll
      for (int nt = 0; nt < 4; nt++) b[nt] = *(half8*)&Bs[cur][wn * 64 + nt * 16 + l15][kk * 32 + quad * 8];
      #pragma unroll
      for (int mt = 0; mt < 4; mt++)
        #pragma unroll
        for (int nt = 0; nt < 4; nt++)
          acc[mt * 4 + nt] = MFMA16(a[mt], b[nt], acc[mt * 4 + nt], 0, 0, 0);
    }
    if (t < 11) {
      #pragma unroll
      for (int i = 0; i < 4; i++) {
        int f = i * 256 + tid, row = f >> 3, c8 = (f & 7) << 3;
        *(half8*)&As[cur ^ 1][row][c8] = ra[i];
        *(half8*)&Bs[cur ^ 1][row][c8] = rb[i];
      }
      __syncthreads();
      cur ^= 1;
    }
  }
  for (int mt = 0; mt < 4; mt++)
    for (int nt = 0; nt < 4; nt++) {
      int d = bn * 128 + wn * 64 + nt * 16 + l15;
      int tok0 = bm * 128 + wm * 64 + mt * 16 + quad * 4;
      int bb = tok0 >> 11, ntok = tok0 & 2047;
      half4v p;
      for (int r = 0; r < 4; r++) p[r] = f2h(acc[mt * 4 + nt][r]);
      *(half4v*)(Vt + (size_t)(bb * 768 + d) * 2048 + ntok) = p;
    }
}

// ---------------- flash attention v12: Qtile=64, 1 block/CU, cross-iter ring prefetch ----------------
__global__ __launch_bounds__(512, 2) void attn_kernel(const _Float16* __restrict__ H,
    const float* __restrict__ X, const _Float16* __restrict__ Vt, float* __restrict__ out) {
  __shared__ _Float16 Qs[64][776];   // 99,328 B
  __shared__ _Float16 Pl[64][136];   // 17,408 B
  __shared__ float pm[8][64];        //  2,048 B
  __shared__ float psum[8][64];      //  2,048 B
  __shared__ float m_run[64], l_run[64], gmax[64], galpha[64];  // 1,024 B

  int id = blockIdx.x;
  int b = id & 7;            // batch -> XCD
  int q0 = (id >> 3) * 64;   // 32 q-tiles per batch
  int tid = threadIdx.x;
  int lane = tid & 63, w = tid >> 6;   // w in 0..7
  int l15 = lane & 15, quad = lane >> 4;

  if (tid < 64) { m_run[tid] = -1e30f; l_run[tid] = 0.f; }

  floatx4 accO[24];   // [nt][ss]: 6 d-tiles x 4 q-subtiles; wave owns d [w*96,+96)
  for (int i = 0; i < 24; i++) accO[i] = (floatx4){0.f, 0.f, 0.f, 0.f};

  const float*    Xq    = X + (size_t)(b * 2048 + q0) * 768;
  const _Float16* Hbase = H + (size_t)(b * 2048) * 768;
  const _Float16* Vbase = Vt + (size_t)b * 768 * 2048;
  const _Float16* KrBase = Hbase + (size_t)(w * 16 + l15) * 768 + quad * 8;
  const _Float16* VrBase = Vbase + (size_t)(w * 96 + l15) * 2048 + quad * 8;

  // stage queries: X fp32 -> Qs fp16 (64 x 768), 6144 half8 chunks / 512 thr
  for (int i = 0; i < 12; i++) {
    int f = i * 512 + tid;
    int row = f / 96, c8 = (f % 96) * 8;
    float4 a = *(const float4*)(Xq + (size_t)row * 768 + c8);
    float4 c = *(const float4*)(Xq + (size_t)row * 768 + c8 + 4);
    *(half8*)&Qs[row][c8] = (half8){f2h(a.x), f2h(a.y), f2h(a.z), f2h(a.w),
                                    f2h(c.x), f2h(c.y), f2h(c.z), f2h(c.w)};
  }

  // prime rings for m0=0 (chunks 0..7 of K row-slice and V tile)
  half8 kpre[8], vpre[8];
  #pragma unroll
  for (int i = 0; i < 8; i++) kpre[i] = *(const half8*)(KrBase + i * 32);
  #pragma unroll
  for (int i = 0; i < 8; i++)
    vpre[i] = *(const half8*)(VrBase + (size_t)(i % 6) * 16 * 2048 + (i / 6) * 32);
  __syncthreads();

  for (int m0 = 0; m0 < 2048; m0 += 128) {
    int mn = (m0 + 128) & 2047;   // next tile (wraps to 0 at the end; in-bounds)
    const _Float16* Kr  = KrBase + (size_t)m0 * 768;
    const _Float16* KrN = KrBase + (size_t)mn * 768;
    const _Float16* vb0 = VrBase + m0;
    const _Float16* vbN = VrBase + mn;
    // ======== S = Q H^T : 64 q-rows x 128 keys; wave w: keys [w*16,+16) ========
    floatx4 sa[4];
    #pragma unroll
    for (int ss = 0; ss < 4; ss++) sa[ss] = (floatx4){0.f, 0.f, 0.f, 0.f};
    #pragma unroll
    for (int kb = 0; kb < 24; kb++) {
      half8 kcur = kpre[kb & 7];
      if (kb + 8 < 24)   // refill with current tile's chunk kb+8
        kpre[kb & 7] = *(const half8*)(Kr + (kb + 8) * 32);
      else               // tail: prefetch NEXT tile's chunk (kb+8-24)
        kpre[kb & 7] = *(const half8*)(KrN + (kb + 8 - 24) * 32);
      #pragma unroll
      for (int ss = 0; ss < 4; ss++) {
        half8 qa = *(half8*)&Qs[ss * 16 + l15][kb * 32 + quad * 8];
        sa[ss] = MFMA16(qa, kcur, sa[ss], 0, 0, 0);
      }
    }

    // ======== wave-local row max over this wave's 16 keys ========
    float mv[16];
    #pragma unroll
    for (int i = 0; i < 16; i++) mv[i] = sa[i >> 2][i & 3];
    #pragma unroll
    for (int mask = 1; mask <= 8; mask <<= 1)
      #pragma unroll
      for (int i = 0; i < 16; i++) mv[i] = fmaxf(mv[i], __shfl_xor(mv[i], mask));
    if (l15 == 0) {
      #pragma unroll
      for (int i = 0; i < 16; i++) pm[w][(i >> 2) * 16 + quad * 4 + (i & 3)] = mv[i];
    }
    __syncthreads();   // barrier A: pm visible
    if (tid < 64) {    // combine wave maxes once; update m_run (only these threads touch it)
      float mo = m_run[tid];
      float mn2 = mo;
      #pragma unroll
      for (int w2 = 0; w2 < 8; w2++) mn2 = fmaxf(mn2, pm[w2][tid]);
      gmax[tid] = mn2;
      galpha[tid] = __expf(mo - mn2);   // first tile: exp(-1e30)=0
      m_run[tid] = mn2;
    }
    __syncthreads();   // barrier A2: gmax/galpha visible
    // ======== exp in regs -> Pl (A-layout), row partial sums ========
    float pr[16], al[16];
    #pragma unroll
    for (int i = 0; i < 16; i++) {
      int ss = i >> 2, r = i & 3;
      int row = ss * 16 + quad * 4 + r;
      float mn2 = gmax[row];
      al[i] = galpha[row];
      float p = __expf(sa[ss][r] - mn2);
      pr[i] = p;
      Pl[row][w * 16 + l15] = f2h(p);
    }
    #pragma unroll
    for (int mask = 1; mask <= 8; mask <<= 1)
      #pragma unroll
      for (int i = 0; i < 16; i++) pr[i] += __shfl_xor(pr[i], mask);
    if (l15 == 0) {
      #pragma unroll
      for (int i = 0; i < 16; i++) psum[w][(i >> 2) * 16 + quad * 4 + (i & 3)] = pr[i];
    }
    // rescale O while Pl/psum settle
    #pragma unroll
    for (int nt = 0; nt < 6; nt++)
      #pragma unroll
      for (int i = 0; i < 16; i++)
        accO[nt * 4 + (i >> 2)][i & 3] *= al[i];
    __syncthreads();   // barrier B: Pl + psum visible
    if (tid < 64) {    // fold l_run (parallel over 64 rows)
      float s = 0.f;
      #pragma unroll
      for (int w2 = 0; w2 < 8; w2++) s += psum[w2][tid];
      l_run[tid] = l_run[tid] * galpha[tid] + s;
    }
    // ======== O += P V : 128 keys, 6 d-tiles x 4 q-subtiles ========
    #pragma unroll
    for (int ks = 0; ks < 4; ks++) {
      half8 pa[4];
      #pragma unroll
      for (int ss = 0; ss < 4; ss++) pa[ss] = *(half8*)&Pl[ss * 16 + l15][ks * 32 + quad * 8];
      #pragma unroll
      for (int nt = 0; nt < 6; nt++) {
        int idx = ks * 6 + nt;
        half8 vcur = vpre[idx & 7];
        int nidx = idx + 8;
        if (nidx < 24)   // refill with current tile's chunk nidx
          vpre[idx & 7] = *(const half8*)(vb0 + (size_t)(nidx % 6) * 16 * 2048 + (nidx / 6) * 32);
        else             // tail: prefetch NEXT tile's chunk (nidx-24)
          vpre[idx & 7] = *(const half8*)(vbN + (size_t)((nidx - 24) % 6) * 16 * 2048 + ((nidx - 24) / 6) * 32);
        #pragma unroll
        for (int ss = 0; ss < 4; ss++)
          accO[nt * 4 + ss] = MFMA16(pa[ss], vcur, accO[nt * 4 + ss], 0, 0, 0);
      }
    }
  }
  __syncthreads();   // l_run final visible
  float il[16];
  #pragma unroll
  for (int i = 0; i < 16; i++) {
    int row = (i >> 2) * 16 + quad * 4 + (i & 3);
    il[i] = 1.f / l_run[row];
  }
  #pragma unroll
  for (int nt = 0; nt < 6; nt++)
    #pragma unroll
    for (int ss = 0; ss < 4; ss++) {
      int d = w * 96 + nt * 16 + l15;
      #pragma unroll
      for (int r = 0; r < 4; r++) {
        int row = q0 + ss * 16 + quad * 4 + r;
        out[(size_t)(b * 2048 + row) * 768 + d] = accO[nt * 4 + ss][r] * il[ss * 4 + r];
      }
    }
}

extern "C" void kernel_launch(void* const* d_in, const int* in_sizes, int n_in,
                              void* d_out, int out_size, void* d_ws, size_t ws_size,
                              hipStream_t stream) {
  (void)in_sizes; (void)n_in; (void)out_size; (void)ws_size;
  const float* X  = (const float*)d_in[0];
  const float* Wq = (const float*)d_in[1];
  const float* Wk = (const float*)d_in[2];
  const float* Wv = (const float*)d_in[3];
  float* out = (float*)d_out;

  char* ws = (char*)d_ws;
  _Float16* H  = (_Float16*)ws;                        // 25,165,824 B
  _Float16* Vt = (_Float16*)(ws + 25165824);           // 25,165,824 B

  // scratch in d_out, consumed before attn writes out:
  _Float16* Mh  = (_Float16*)d_out;                       // 1,179,648 B @ 0
  _Float16* WvT = (_Float16*)((char*)d_out + 2359296);    // 1,179,648 B
  _Float16* Xh  = (_Float16*)((char*)d_out + 4194304);    // 25,165,824 B (ends 29.4 MB < 50.3 MB)

  cast_x_kernel<<<2048, 256, 0, stream>>>(X, Xh);
  mm_small_kernel<<<dim3(6, 6), 256, 0, stream>>>(Wq, Wk, Mh);
  pack_wv_kernel<<<dim3(24, 24), dim3(32, 8), 0, stream>>>(Wv, WvT);
  proj_h_kernel<<<dim3(6, 128), 256, 0, stream>>>(Xh, Mh, H);
  proj_v_kernel<<<dim3(6, 128), 256, 0, stream>>>(Xh, WvT, Vt);
  attn_kernel<<<256, 512, 0, stream>>>(H, X, Vt, out);
}